// Round 1
// 107.327 us; speedup vs baseline: 1.0143x; 1.0143x over previous
//
#include <hip/hip_runtime.h>

#define DIM 128
#define NN 72
#define BB 2
#define NSQ (NN*NN)        // 5184
#define NROWS (BB*NSQ)     // 10368
#define BN (BB*NN)         // 144
#define ZBLOCKS (NROWS/16) // 648

// ---------------------------------------------------------------------------
// Kernel 1: z = path@W_hz + b_hz (16 rows/blk), ALSO writes zT (transposed
// (i,j) layout) so k_trop_out's zj reads are k-sequential. Blocks 648..665
// compute P1/P3 = node@W1/W3. W-stream prefetch depth 2 (8 K per iter).
// ---------------------------------------------------------------------------
__global__ __launch_bounds__(256, 4) void k_phase1(const float* __restrict__ path,
                                                   const float* __restrict__ Whz,
                                                   const float* __restrict__ bhz,
                                                   float* __restrict__ z,
                                                   float* __restrict__ zT,
                                                   const float* __restrict__ node,
                                                   const float* __restrict__ Wzz,
                                                   float* __restrict__ P1,
                                                   float* __restrict__ P3) {
    __shared__ float rows[16 * DIM];   // 8 KB
    const int t = threadIdx.x;

    if (blockIdx.x < ZBLOCKS) {
        const int r0 = blockIdx.x * 16;
        {
            float4* rs = (float4*)rows;
            const float4* pg = (const float4*)(path + r0 * DIM);
            rs[t]       = pg[t];
            rs[t + 256] = pg[t + 256];
        }
        __syncthreads();

        const int e2 = t & 63;
        const int rg = t >> 6;
        float2 bz = *(const float2*)&bhz[2 * e2];
        float2 acc[4];
#pragma unroll
        for (int r = 0; r < 4; r++) acc[r] = bz;

        const float* Wp = Whz + 2 * e2;
        float2 w0[4], w1[4], n0[4], n1[4];
#pragma unroll
        for (int dd = 0; dd < 4; dd++) {
            w0[dd] = *(const float2*)&Wp[dd * DIM];
            w1[dd] = *(const float2*)&Wp[(4 + dd) * DIM];
        }
        for (int d8 = 0; d8 < 16; d8++) {
            if (d8 < 15) {
#pragma unroll
                for (int dd = 0; dd < 4; dd++) {
                    n0[dd] = *(const float2*)&Wp[(8 * d8 + 8 + dd) * DIM];
                    n1[dd] = *(const float2*)&Wp[(8 * d8 + 12 + dd) * DIM];
                }
            }
            float4 pa[4], pb[4];
#pragma unroll
            for (int r = 0; r < 4; r++) {
                pa[r] = *(const float4*)&rows[(rg + 4 * r) * DIM + 8 * d8];
                pb[r] = *(const float4*)&rows[(rg + 4 * r) * DIM + 8 * d8 + 4];
            }
#pragma unroll
            for (int dd = 0; dd < 4; dd++)
#pragma unroll
                for (int r = 0; r < 4; r++) {
                    float pv = ((const float*)&pa[r])[dd];
                    acc[r].x = fmaf(pv, w0[dd].x, acc[r].x);
                    acc[r].y = fmaf(pv, w0[dd].y, acc[r].y);
                }
#pragma unroll
            for (int dd = 0; dd < 4; dd++)
#pragma unroll
                for (int r = 0; r < 4; r++) {
                    float pv = ((const float*)&pb[r])[dd];
                    acc[r].x = fmaf(pv, w1[dd].x, acc[r].x);
                    acc[r].y = fmaf(pv, w1[dd].y, acc[r].y);
                }
#pragma unroll
            for (int dd = 0; dd < 4; dd++) { w0[dd] = n0[dd]; w1[dd] = n1[dd]; }
        }
#pragma unroll
        for (int r = 0; r < 4; r++) {
            int row = r0 + rg + 4 * r;
            *(float2*)&z[row * DIM + 2 * e2] = acc[r];
            int b  = row / NSQ;
            int ij = row - b * NSQ;
            int i  = ij / NN;
            int j  = ij - i * NN;
            *(float2*)&zT[(b * NSQ + j * NN + i) * DIM + 2 * e2] = acc[r];
        }
    } else {
        const int r0 = (blockIdx.x - ZBLOCKS) * 8;
        {
            float4* rs = (float4*)rows;
            const float4* ng = (const float4*)(node + r0 * DIM);
            rs[t] = ng[t];
        }
        __syncthreads();
        const int e  = t & 127;
        const int rr = t >> 7;
        float a1[4] = {0.f, 0.f, 0.f, 0.f};
        float a3[4] = {0.f, 0.f, 0.f, 0.f};
        const float* W1 = Wzz + e;
        const float* W3 = Wzz + 2 * DIM * DIM + e;
        for (int d = 0; d < DIM; d++) {
            float w1 = W1[d * DIM];
            float w3 = W3[d * DIM];
#pragma unroll
            for (int s = 0; s < 4; s++) {
                float pv = rows[(rr + 2 * s) * DIM + d];
                a1[s] = fmaf(pv, w1, a1[s]);
                a3[s] = fmaf(pv, w3, a3[s]);
            }
        }
#pragma unroll
        for (int s = 0; s < 4; s++) {
            int m = r0 + rr + 2 * s;
            P1[m * DIM + e] = a1[s];
            P3[m * DIM + e] = a3[s];
        }
    }
}

// ---------------------------------------------------------------------------
// Kernel 2: fused tropical conv + output GEMM. Phase 2 reads 8 k-sequential
// streams (zi from z, zj from zT), 4 k's per group per ty => 32 loads in
// flight. Phase 3 GEMM sources zmax tile from LDS; W2 prefetch depth 2.
//
// XCD-region swizzle: 648 blocks = 8 XCDs x 81 slots. Under round-robin
// block->XCD dispatch, blk&7 == XCD id. Each XCD gets one compact region:
// (b, 2x2 quadrant of the 18x18 tile grid) = 9x9 tiles. Per-XCD working set
// = 36 zi-rows + 36 zT-rows x 72 k x 512B = 2.66 MB < 4 MB L2 (was 10.6 MB
// under the linear map -> L2 thrash -> ~191 MB served from L3).
// ---------------------------------------------------------------------------
__global__ __launch_bounds__(256, 3) void k_trop_out(
        const float* __restrict__ z,   const float* __restrict__ zT,
        const float* __restrict__ Wzz, const float* __restrict__ bzz,
        const float* __restrict__ P1,  const float* __restrict__ P3,
        float* __restrict__ out) {
    __shared__ float rows[16 * DIM];   // zmax tile (8 KB)
    __shared__ float comb[16 * DIM];   // k-split merge (8 KB)
    const int t   = threadIdx.x;
    const int blk = blockIdx.x;
    // XCD-region decode (bijective on [0,648)):
    const int xcd  = blk & 7;     // region id: b = xcd>>2, quadrant = xcd&3
    const int slot = blk >> 3;    // 0..80, walks the 9x9 region
    const int b  = xcd >> 2;
    const int qi = (xcd >> 1) & 1;
    const int qj = xcd & 1;
    const int il = slot / 9;
    const int jl = slot - il * 9;
    const int it = qi * 9 + il;
    const int jt = qj * 9 + jl;
    const int i0 = it * 4, j0 = jt * 4;
    const int d  = t & 127;
    const int ty = t >> 7;    // k parity
    const float* zb  = z  + b * NSQ * DIM;
    const float* zTb = zT + b * NSQ * DIM;

    // ---- phase 2: max-plus over k; 2-way k-split, groups of 4 k's ---------
    {
        float acc[16];
#pragma unroll
        for (int q = 0; q < 16; q++) acc[q] = -3.402823466e38f;

        float cur[32], nxt[32];   // [kk*8 + s]: s=0..3 zi, 4..7 zj
#pragma unroll
        for (int kk = 0; kk < 4; kk++) {
            int k = ty + 2 * kk;
#pragma unroll
            for (int s = 0; s < 4; s++) {
                cur[kk * 8 + s]     = zb [((i0 + s) * NN + k) * DIM + d];
                cur[kk * 8 + 4 + s] = zTb[((j0 + s) * NN + k) * DIM + d];
            }
        }
        for (int g = 0; g < 9; g++) {
            if (g < 8) {
#pragma unroll
                for (int kk = 0; kk < 4; kk++) {
                    int k = ty + 2 * kk + 8 * (g + 1);
#pragma unroll
                    for (int s = 0; s < 4; s++) {
                        nxt[kk * 8 + s]     = zb [((i0 + s) * NN + k) * DIM + d];
                        nxt[kk * 8 + 4 + s] = zTb[((j0 + s) * NN + k) * DIM + d];
                    }
                }
            }
#pragma unroll
            for (int kk = 0; kk < 4; kk++)
#pragma unroll
                for (int a = 0; a < 4; a++)
#pragma unroll
                    for (int c = 0; c < 4; c++)
                        acc[a * 4 + c] = fmaxf(acc[a * 4 + c],
                                               cur[kk * 8 + a] + cur[kk * 8 + 4 + c]);
#pragma unroll
            for (int q = 0; q < 32; q++) cur[q] = nxt[q];
        }

        if (ty == 1) {
#pragma unroll
            for (int q = 0; q < 16; q++) comb[q * DIM + d] = acc[q];
        }
        __syncthreads();
        if (ty == 0) {
#pragma unroll
            for (int a = 0; a < 4; a++)
#pragma unroll
                for (int c = 0; c < 4; c++) {
                    int q = a * 4 + c;
                    float m = fmaxf(acc[q], comb[q * DIM + d]);
                    int idx = ((i0 + a) * NN + (j0 + c)) * DIM + d;
                    rows[q * DIM + d] = fmaxf(m, zb[idx]);
                }
        }
    }
    __syncthreads();

    // ---- phase 3: out = relu(zmax@W2 + P1[b,i] + P3[b,j] + b_zz) ----------
    {
        const int e2 = t & 63;
        const int rg = t >> 6;
        float2 acc[4];
#pragma unroll
        for (int r = 0; r < 4; r++) acc[r] = make_float2(0.f, 0.f);

        const float* Wp = Wzz + DIM * DIM + 2 * e2;   // W2 block
        float2 w0[4], w1[4], n0[4], n1[4];
#pragma unroll
        for (int dd = 0; dd < 4; dd++) {
            w0[dd] = *(const float2*)&Wp[dd * DIM];
            w1[dd] = *(const float2*)&Wp[(4 + dd) * DIM];
        }
        for (int d8 = 0; d8 < 16; d8++) {
            if (d8 < 15) {
#pragma unroll
                for (int dd = 0; dd < 4; dd++) {
                    n0[dd] = *(const float2*)&Wp[(8 * d8 + 8 + dd) * DIM];
                    n1[dd] = *(const float2*)&Wp[(8 * d8 + 12 + dd) * DIM];
                }
            }
            float4 pa[4], pb[4];
#pragma unroll
            for (int r = 0; r < 4; r++) {
                pa[r] = *(const float4*)&rows[(rg + 4 * r) * DIM + 8 * d8];
                pb[r] = *(const float4*)&rows[(rg + 4 * r) * DIM + 8 * d8 + 4];
            }
#pragma unroll
            for (int dd = 0; dd < 4; dd++)
#pragma unroll
                for (int r = 0; r < 4; r++) {
                    float pv = ((const float*)&pa[r])[dd];
                    acc[r].x = fmaf(pv, w0[dd].x, acc[r].x);
                    acc[r].y = fmaf(pv, w0[dd].y, acc[r].y);
                }
#pragma unroll
            for (int dd = 0; dd < 4; dd++)
#pragma unroll
                for (int r = 0; r < 4; r++) {
                    float pv = ((const float*)&pb[r])[dd];
                    acc[r].x = fmaf(pv, w1[dd].x, acc[r].x);
                    acc[r].y = fmaf(pv, w1[dd].y, acc[r].y);
                }
#pragma unroll
            for (int dd = 0; dd < 4; dd++) { w0[dd] = n0[dd]; w1[dd] = n1[dd]; }
        }

        float2 bz = *(const float2*)&bzz[2 * e2];
#pragma unroll
        for (int r = 0; r < 4; r++) {
            int q = rg + 4 * r;        // LDS row index = a*4+c
            int a = q >> 2, c = q & 3;
            int orow = b * NSQ + (i0 + a) * NN + (j0 + c);
            float2 v1 = *(const float2*)&P1[(b * NN + i0 + a) * DIM + 2 * e2];
            float2 v3 = *(const float2*)&P3[(b * NN + j0 + c) * DIM + 2 * e2];
            float ox = fmaxf(acc[r].x + v1.x + v3.x + bz.x, 0.f);
            float oy = fmaxf(acc[r].y + v1.y + v3.y + bz.y, 0.f);
            *(float2*)&out[orow * DIM + 2 * e2] = make_float2(ox, oy);
        }
    }
}

extern "C" void kernel_launch(void* const* d_in, const int* in_sizes, int n_in,
                              void* d_out, int out_size, void* d_ws, size_t ws_size,
                              hipStream_t stream) {
    const float* node = (const float*)d_in[0];
    const float* path = (const float*)d_in[1];
    const float* Whz  = (const float*)d_in[2];
    const float* bhz  = (const float*)d_in[3];
    const float* Wzz  = (const float*)d_in[4];
    const float* bzz  = (const float*)d_in[5];
    float* out = (float*)d_out;

    float* z  = (float*)d_ws;
    float* zT = z  + NROWS * DIM;
    float* P1 = zT + NROWS * DIM;
    float* P3 = P1 + BN * DIM;

    hipLaunchKernelGGL(k_phase1,   dim3(ZBLOCKS + 18), dim3(256), 0, stream,
                       path, Whz, bhz, z, zT, node, Wzz, P1, P3);
    hipLaunchKernelGGL(k_trop_out, dim3(BB * 18 * 18), dim3(256), 0, stream,
                       z, zT, Wzz, bzz, P1, P3, out);
}